// Round 10
// baseline (510.700 us; speedup 1.0000x reference)
//
#include <hip/hip_runtime.h>
#include <math.h>

#define SB 8192
#define NB 32
#define WC 64
#define NM 16
#define NKC 32   // 2*NM (cos,sin interleaved)
#define NP 24
#define NSC 32   // K-split slices per batch for k_dft
#define LP 132   // padded LDS row length (128 + 4)

// h layout: h[b][ch][s] (s contiguous)
// ws layout (float offsets):
//   h    : 0         (B*W*S = 16777216)
//   T    : 16777216  (S*32  = 262144)
//   xf   : 17039360  (B*W*32 = 65536)
//   of   : 17104896  (B*W*32 = 65536)
//   icaT : 17170432  (128*24 = 3072)
// k_dft partials (32*32*2048 = 2M floats) live in the tc output region (dead until k_final).

__global__ __launch_bounds__(256) void k_table(float* __restrict__ T) {
    int s = blockIdx.x * 256 + threadIdx.x;   // exactly 8192 threads
    float* row = T + (size_t)s * NKC;
    #pragma unroll
    for (int k = 0; k < NM; ++k) {
        int m = (k * s) & (SB - 1);           // exact phase mod S
        double ang = (double)m * (6.283185307179586476925286766559 / (double)SB);
        row[2 * k]     = (float)cos(ang);
        row[2 * k + 1] = (float)sin(ang);
    }
}

// icaT[c][p] = fc2_w[0][c] * ica_w[p][c]
__global__ __launch_bounds__(256) void k_prep(const float* __restrict__ ica_w,
                                              const float* __restrict__ fc2_w,
                                              float* __restrict__ icaT) {
    int tid = blockIdx.x * 256 + threadIdx.x;   // exactly 3072
    int c = tid / NP;
    int p = tid - c * NP;
    icaT[c * NP + p] = ica_w[p * 128 + c] * fc2_w[c];
}

// lift: h[b][w][s] = x[b][s][0]*fc0_w[w][0] + x[b][s][1]*fc0_w[w][1] + fc0_b[w]
__global__ __launch_bounds__(256) void k_lift(const float* __restrict__ x,
                                              const float* __restrict__ fc0_w,
                                              const float* __restrict__ fc0_b,
                                              float* __restrict__ h) {
    int b = blockIdx.y;
    int s = blockIdx.x * 256 + threadIdx.x;
    float2 xv = ((const float2*)x)[(size_t)b * SB + s];
    #pragma unroll
    for (int w = 0; w < WC; ++w) {
        float v = fmaf(xv.x, fc0_w[2 * w], fmaf(xv.y, fc0_w[2 * w + 1], fc0_b[w]));
        h[((size_t)(b * WC + w)) * SB + s] = v;
    }
}

// forward DFT as LDS-staged GEMM. NSC=32: block = (b, 256-s K-slice), 2 subtiles.
__global__ __launch_bounds__(256) void k_dft(const float* __restrict__ h,
                                             const float* __restrict__ T,
                                             float* __restrict__ xfp) {
    __shared__ float hT[64][LP];   // 33792 B
    __shared__ float Tt[32][LP];   // 16896 B
    int blk = blockIdx.x;          // b*NSC + sc
    int b  = blk >> 5;
    int sc = blk & (NSC - 1);
    int t  = threadIdx.x;
    int g = t >> 4, j = t & 15;

    float acc[4][2];
    #pragma unroll
    for (int i = 0; i < 4; ++i) { acc[i][0] = 0.f; acc[i][1] = 0.f; }

    const float* hb = h + (size_t)b * WC * SB;
    int ch   = t >> 2;
    int part = t & 3;
    int sl   = t >> 1;
    int jj0  = (t & 1) * 16;

    for (int st = 0; st < 2; ++st) {
        int s_base = sc * 256 + st * 128;

        const float* hrow = hb + (size_t)ch * SB + s_base;
        #pragma unroll
        for (int r = 0; r < 8; ++r) {
            int so = (part + 4 * r) * 4;
            *(float4*)&hT[ch][so] = *(const float4*)(hrow + so);
        }
        {
            const float4* src = (const float4*)(T + (size_t)(s_base + sl) * NKC + jj0);
            float4 a = src[0], c4 = src[1], d = src[2], e = src[3];
            Tt[jj0 +  0][sl] = a.x;  Tt[jj0 +  1][sl] = a.y;
            Tt[jj0 +  2][sl] = a.z;  Tt[jj0 +  3][sl] = a.w;
            Tt[jj0 +  4][sl] = c4.x; Tt[jj0 +  5][sl] = c4.y;
            Tt[jj0 +  6][sl] = c4.z; Tt[jj0 +  7][sl] = c4.w;
            Tt[jj0 +  8][sl] = d.x;  Tt[jj0 +  9][sl] = d.y;
            Tt[jj0 + 10][sl] = d.z;  Tt[jj0 + 11][sl] = d.w;
            Tt[jj0 + 12][sl] = e.x;  Tt[jj0 + 13][sl] = e.y;
            Tt[jj0 + 14][sl] = e.z;  Tt[jj0 + 15][sl] = e.w;
        }
        __syncthreads();

        #pragma unroll 4
        for (int step = 0; step < 32; ++step) {
            int s4 = step * 4;
            float4 ta = *(const float4*)&Tt[j][s4];
            float4 tb = *(const float4*)&Tt[j + 16][s4];
            #pragma unroll
            for (int i = 0; i < 4; ++i) {
                float4 hv = *(const float4*)&hT[g * 4 + i][s4];
                acc[i][0] = fmaf(hv.x, ta.x, fmaf(hv.y, ta.y,
                            fmaf(hv.z, ta.z, fmaf(hv.w, ta.w, acc[i][0]))));
                acc[i][1] = fmaf(hv.x, tb.x, fmaf(hv.y, tb.y,
                            fmaf(hv.z, tb.z, fmaf(hv.w, tb.w, acc[i][1]))));
            }
        }
        __syncthreads();
    }

    float* dst = xfp + ((size_t)(sc * NB + b)) * 2048;
    #pragma unroll
    for (int i = 0; i < 4; ++i) {
        dst[(g * 4 + i) * 32 + j]      = acc[i][0];
        dst[(g * 4 + i) * 32 + j + 16] = acc[i][1];
    }
}

// reduce K-split partials
__global__ __launch_bounds__(256) void k_red(const float* __restrict__ xfp,
                                             float* __restrict__ xf) {
    int idx = blockIdx.x * 256 + threadIdx.x;   // exactly 65536
    int b = idx >> 11;
    int r = idx & 2047;
    float s = 0.f;
    #pragma unroll 8
    for (int sc = 0; sc < NSC; ++sc)
        s += xfp[((size_t)(sc * NB + b)) * 2048 + r];
    xf[idx] = s;
}

// mode mix: of[b][o][2k] = alpha*Re, of[b][o][2k+1] = -alpha*Im
__global__ __launch_bounds__(256) void k_mix(const float* __restrict__ xf,
                                             const float* __restrict__ wr,
                                             const float* __restrict__ wi,
                                             float* __restrict__ of) {
    int tid = blockIdx.x * 256 + threadIdx.x;   // exactly 32768
    int k = tid & 15;
    int o = (tid >> 4) & 63;
    int b = tid >> 10;
    float orr = 0.f, oii = 0.f;
    const float2* xfb = (const float2*)(xf + (size_t)b * WC * NKC);
    #pragma unroll 4
    for (int i = 0; i < WC; ++i) {
        float2 cs = xfb[i * NM + k];
        float wrv = wr[(i * WC + o) * NM + k];
        float wiv = wi[(i * WC + o) * NM + k];
        orr = fmaf(cs.x, wrv, fmaf(cs.y, wiv, orr));    // xfr*wr - xfi*wi
        oii = fmaf(cs.x, wiv, fmaf(-cs.y, wrv, oii));   // xfr*wi + xfi*wr
    }
    float alpha = (k == 0 ? 1.f : 2.f) / (float)SB;
    float2 res = make_float2(alpha * orr, -alpha * oii);
    ((float2*)of)[(size_t)(b * WC + o) * NM + k] = res;
}

// fused inverse-DFT + pointwise conv + bias + relu, in-place on h.
// o-split (block owns 32 of 64 output channels) + 2-column register blocking:
// acc0[32]+acc1[32]+xs ~ 110 VGPR at (256,2) -> 4 waves/SIMD, no remat.
// Still 8 FMAs per broadcast ds_read_b128.
__global__ __launch_bounds__(256, 2) void k_update(float* __restrict__ h,
                                                   const float* __restrict__ T,
                                                   const float* __restrict__ of,
                                                   const float* __restrict__ pw,
                                                   const float* __restrict__ pwb,
                                                   int relu) {
    __shared__ float At[96][32];   // 12 KB; At[k][o'] for this block's o-half
    int b  = blockIdx.y;
    int sc = blockIdx.x >> 1;
    int oh = blockIdx.x & 1;       // o-half: 0 -> o 0..31, 1 -> o 32..63
    int s0 = sc * 512 + threadIdx.x;   // second column: s0 + 256
    int ob = oh * 32;

    const float* ofb = of + (size_t)b * WC * NKC;
    for (int e = threadIdx.x; e < 96 * 32; e += 256) {
        int k = e >> 5, o = e & 31;
        At[k][o] = (k < 64) ? pw[(ob + o) * 64 + k] : ofb[(ob + o) * 32 + (k - 64)];
    }

    float* hcol0 = h + (size_t)b * WC * SB + s0;
    float* hcol1 = hcol0 + 256;
    float acc0[32], acc1[32];
    #pragma unroll
    for (int o = 0; o < 32; ++o) { acc0[o] = pwb[ob + o]; acc1[o] = pwb[ob + o]; }
    __syncthreads();

    // pointwise part: K = 64 (all input channels), chunks of 8
    for (int kc = 0; kc < 8; ++kc) {
        float xs0[8], xs1[8];
        #pragma unroll
        for (int u = 0; u < 8; ++u) {
            xs0[u] = hcol0[(size_t)(kc * 8 + u) * SB];
            xs1[u] = hcol1[(size_t)(kc * 8 + u) * SB];
        }
        #pragma unroll
        for (int u = 0; u < 8; ++u) {
            const float4* arow = (const float4*)At[kc * 8 + u];
            #pragma unroll
            for (int o4 = 0; o4 < 8; ++o4) {
                float4 a = arow[o4];
                acc0[o4*4+0] = fmaf(a.x, xs0[u], acc0[o4*4+0]);
                acc0[o4*4+1] = fmaf(a.y, xs0[u], acc0[o4*4+1]);
                acc0[o4*4+2] = fmaf(a.z, xs0[u], acc0[o4*4+2]);
                acc0[o4*4+3] = fmaf(a.w, xs0[u], acc0[o4*4+3]);
                acc1[o4*4+0] = fmaf(a.x, xs1[u], acc1[o4*4+0]);
                acc1[o4*4+1] = fmaf(a.y, xs1[u], acc1[o4*4+1]);
                acc1[o4*4+2] = fmaf(a.z, xs1[u], acc1[o4*4+2]);
                acc1[o4*4+3] = fmaf(a.w, xs1[u], acc1[o4*4+3]);
            }
        }
    }
    // inverse-DFT part: K = 32 modes, chunks of 8
    const float4* Trow0 = (const float4*)(T + (size_t)s0 * NKC);
    const float4* Trow1 = (const float4*)(T + (size_t)(s0 + 256) * NKC);
    for (int kc = 0; kc < 4; ++kc) {
        float4 v0 = Trow0[kc * 2], v1 = Trow0[kc * 2 + 1];
        float4 w0 = Trow1[kc * 2], w1v = Trow1[kc * 2 + 1];
        float xs0[8] = {v0.x, v0.y, v0.z, v0.w, v1.x, v1.y, v1.z, v1.w};
        float xs1[8] = {w0.x, w0.y, w0.z, w0.w, w1v.x, w1v.y, w1v.z, w1v.w};
        #pragma unroll
        for (int u = 0; u < 8; ++u) {
            const float4* arow = (const float4*)At[64 + kc * 8 + u];
            #pragma unroll
            for (int o4 = 0; o4 < 8; ++o4) {
                float4 a = arow[o4];
                acc0[o4*4+0] = fmaf(a.x, xs0[u], acc0[o4*4+0]);
                acc0[o4*4+1] = fmaf(a.y, xs0[u], acc0[o4*4+1]);
                acc0[o4*4+2] = fmaf(a.z, xs0[u], acc0[o4*4+2]);
                acc0[o4*4+3] = fmaf(a.w, xs0[u], acc0[o4*4+3]);
                acc1[o4*4+0] = fmaf(a.x, xs1[u], acc1[o4*4+0]);
                acc1[o4*4+1] = fmaf(a.y, xs1[u], acc1[o4*4+1]);
                acc1[o4*4+2] = fmaf(a.z, xs1[u], acc1[o4*4+2]);
                acc1[o4*4+3] = fmaf(a.w, xs1[u], acc1[o4*4+3]);
            }
        }
    }

    #pragma unroll
    for (int o = 0; o < 32; ++o) {
        float v0 = acc0[o], v1 = acc1[o];
        if (relu) { v0 = fmaxf(v0, 0.f); v1 = fmaxf(v1, 0.f); }
        hcol0[(size_t)(ob + o) * SB] = v0;
        hcol1[(size_t)(ob + o) * SB] = v1;
    }
}

// final: NO LDS — weights via uniform s_load; hv[64]+acc[24] in regs.
// (256,2): 128-VGPR budget so the allocator keeps hv resident instead of
// rematerializing the 64 h-loads per c-chunk (round-9: VGPR 48 -> 4GB L2 re-fetch).
__global__ __launch_bounds__(256, 2) void k_final(const float* __restrict__ h,
                                                  const float* __restrict__ fc1_w,
                                                  const float* __restrict__ fc1_b,
                                                  const float* __restrict__ icaT,
                                                  const float* __restrict__ ica_b,
                                                  float* __restrict__ out,
                                                  float* __restrict__ tc) {
    int b = blockIdx.y;
    int s = blockIdx.x * 256 + threadIdx.x;

    float hv[64];
    const float* hcol = h + (size_t)b * WC * SB + s;
    #pragma unroll
    for (int i = 0; i < 64; ++i) hv[i] = hcol[(size_t)i * SB];

    float acc[NP];
    #pragma unroll
    for (int p = 0; p < NP; ++p) acc[p] = ica_b[p];

    for (int cc = 0; cc < 16; ++cc) {
        float tv8[8];
        #pragma unroll
        for (int u = 0; u < 8; ++u) {
            int c = cc * 8 + u;
            float t = fc1_b[c];
            const float* w = fc1_w + c * WC;
            #pragma unroll
            for (int i = 0; i < 64; ++i) t = fmaf(w[i], hv[i], t);
            tv8[u] = fmaxf(t, 0.f);
        }
        #pragma unroll
        for (int u = 0; u < 8; ++u) {
            const float* e = icaT + (cc * 8 + u) * NP;
            #pragma unroll
            for (int p = 0; p < NP; ++p)
                acc[p] = fmaf(tv8[u], e[p], acc[p]);
        }
    }

    float osum = 0.f;
    #pragma unroll
    for (int p = 0; p < NP; ++p) osum += acc[p];
    size_t idx = (size_t)b * SB + s;
    out[idx] = osum;

    float4* t4 = (float4*)(tc + idx * NP);   // 96B stride; wave covers 6KB densely
    t4[0] = make_float4(acc[0],  acc[1],  acc[2],  acc[3]);
    t4[1] = make_float4(acc[4],  acc[5],  acc[6],  acc[7]);
    t4[2] = make_float4(acc[8],  acc[9],  acc[10], acc[11]);
    t4[3] = make_float4(acc[12], acc[13], acc[14], acc[15]);
    t4[4] = make_float4(acc[16], acc[17], acc[18], acc[19]);
    t4[5] = make_float4(acc[20], acc[21], acc[22], acc[23]);
}

extern "C" void kernel_launch(void* const* d_in, const int* in_sizes, int n_in,
                              void* d_out, int out_size, void* d_ws, size_t ws_size,
                              hipStream_t stream) {
    const float* x     = (const float*)d_in[0];
    const float* fc0_w = (const float*)d_in[1];
    const float* fc0_b = (const float*)d_in[2];
    const float* cwr   = (const float*)d_in[3];
    const float* cwi   = (const float*)d_in[4];
    const float* pw_w  = (const float*)d_in[5];
    const float* pw_b  = (const float*)d_in[6];
    const float* fc1_w = (const float*)d_in[7];
    const float* fc1_b = (const float*)d_in[8];
    const float* fc2_w = (const float*)d_in[9];
    const float* ica_w = (const float*)d_in[10];
    const float* ica_b = (const float*)d_in[11];

    float* out = (float*)d_out;            // (B,S,1) = 262144
    float* tc  = out + (size_t)NB * SB;    // (B,S,1,24) = 6291456

    float* ws   = (float*)d_ws;
    float* h    = ws;
    float* T    = ws + 16777216;
    float* xf   = ws + 17039360;
    float* of   = ws + 17104896;
    float* icaT = ws + 17170432;
    float* xfp  = tc;                      // k_dft partials scratch (dead until k_final)

    k_table<<<32, 256, 0, stream>>>(T);
    k_prep<<<12, 256, 0, stream>>>(ica_w, fc2_w, icaT);
    k_lift<<<dim3(32, 32), 256, 0, stream>>>(x, fc0_w, fc0_b, h);

    for (int l = 0; l < 4; ++l) {
        k_dft<<<NB * NSC, 256, 0, stream>>>(h, T, xfp);
        k_red<<<256, 256, 0, stream>>>(xfp, xf);
        k_mix<<<128, 256, 0, stream>>>(xf, cwr + (size_t)l * WC * WC * NM,
                                       cwi + (size_t)l * WC * WC * NM, of);
        k_update<<<dim3(32, 32), 256, 0, stream>>>(h, T, of,
                                                   pw_w + (size_t)l * WC * WC,
                                                   pw_b + (size_t)l * WC,
                                                   (l < 3) ? 1 : 0);
    }

    k_final<<<dim3(32, 32), 256, 0, stream>>>(h, fc1_w, fc1_b, icaT, ica_b, out, tc);
}

// Round 11
// 479.344 us; speedup vs baseline: 1.0654x; 1.0654x over previous
//
#include <hip/hip_runtime.h>
#include <math.h>

#define SB 8192
#define NB 32
#define WC 64
#define NM 16
#define NKC 32   // 2*NM (cos,sin interleaved)
#define NP 24
#define NSC 16   // K-split slices per batch for k_dft
#define LP 132   // padded LDS row length (128 + 4)

// h layout: h[b][ch][s] (s contiguous)
// ws layout (float offsets):
//   h    : 0         (B*W*S = 16777216)
//   T    : 16777216  (S*32  = 262144)
//   xf   : 17039360  (B*W*32 = 65536)
//   of   : 17104896  (B*W*32 = 65536)
//   icaT : 17170432  (128*24 = 3072)
// k_dft partials (32*16*2048 = 1M floats) live in the tc output region (dead until k_final).

__global__ __launch_bounds__(256) void k_table(float* __restrict__ T) {
    int s = blockIdx.x * 256 + threadIdx.x;   // exactly 8192 threads
    float* row = T + (size_t)s * NKC;
    #pragma unroll
    for (int k = 0; k < NM; ++k) {
        int m = (k * s) & (SB - 1);           // exact phase mod S
        double ang = (double)m * (6.283185307179586476925286766559 / (double)SB);
        row[2 * k]     = (float)cos(ang);
        row[2 * k + 1] = (float)sin(ang);
    }
}

// icaT[c][p] = fc2_w[0][c] * ica_w[p][c]
__global__ __launch_bounds__(256) void k_prep(const float* __restrict__ ica_w,
                                              const float* __restrict__ fc2_w,
                                              float* __restrict__ icaT) {
    int tid = blockIdx.x * 256 + threadIdx.x;   // exactly 3072
    int c = tid / NP;
    int p = tid - c * NP;
    icaT[c * NP + p] = ica_w[p * 128 + c] * fc2_w[c];
}

// lift: h[b][w][s] = x[b][s][0]*fc0_w[w][0] + x[b][s][1]*fc0_w[w][1] + fc0_b[w]
__global__ __launch_bounds__(256) void k_lift(const float* __restrict__ x,
                                              const float* __restrict__ fc0_w,
                                              const float* __restrict__ fc0_b,
                                              float* __restrict__ h) {
    int b = blockIdx.y;
    int s = blockIdx.x * 256 + threadIdx.x;
    float2 xv = ((const float2*)x)[(size_t)b * SB + s];
    #pragma unroll
    for (int w = 0; w < WC; ++w) {
        float v = fmaf(xv.x, fc0_w[2 * w], fmaf(xv.y, fc0_w[2 * w + 1], fc0_b[w]));
        h[((size_t)(b * WC + w)) * SB + s] = v;
    }
}

// forward DFT as LDS-staged GEMM (round-5/9 structure, NSC=16).
__global__ __launch_bounds__(256) void k_dft(const float* __restrict__ h,
                                             const float* __restrict__ T,
                                             float* __restrict__ xfp) {
    __shared__ float hT[64][LP];   // 33792 B
    __shared__ float Tt[32][LP];   // 16896 B
    int blk = blockIdx.x;          // b*NSC + sc
    int b  = blk >> 4;
    int sc = blk & (NSC - 1);
    int t  = threadIdx.x;
    int g = t >> 4, j = t & 15;

    float acc[4][2];
    #pragma unroll
    for (int i = 0; i < 4; ++i) { acc[i][0] = 0.f; acc[i][1] = 0.f; }

    const float* hb = h + (size_t)b * WC * SB;
    int ch   = t >> 2;
    int part = t & 3;
    int sl   = t >> 1;
    int jj0  = (t & 1) * 16;

    for (int st = 0; st < 4; ++st) {
        int s_base = sc * 512 + st * 128;

        const float* hrow = hb + (size_t)ch * SB + s_base;
        #pragma unroll
        for (int r = 0; r < 8; ++r) {
            int so = (part + 4 * r) * 4;
            *(float4*)&hT[ch][so] = *(const float4*)(hrow + so);
        }
        {
            const float4* src = (const float4*)(T + (size_t)(s_base + sl) * NKC + jj0);
            float4 a = src[0], c4 = src[1], d = src[2], e = src[3];
            Tt[jj0 +  0][sl] = a.x;  Tt[jj0 +  1][sl] = a.y;
            Tt[jj0 +  2][sl] = a.z;  Tt[jj0 +  3][sl] = a.w;
            Tt[jj0 +  4][sl] = c4.x; Tt[jj0 +  5][sl] = c4.y;
            Tt[jj0 +  6][sl] = c4.z; Tt[jj0 +  7][sl] = c4.w;
            Tt[jj0 +  8][sl] = d.x;  Tt[jj0 +  9][sl] = d.y;
            Tt[jj0 + 10][sl] = d.z;  Tt[jj0 + 11][sl] = d.w;
            Tt[jj0 + 12][sl] = e.x;  Tt[jj0 + 13][sl] = e.y;
            Tt[jj0 + 14][sl] = e.z;  Tt[jj0 + 15][sl] = e.w;
        }
        __syncthreads();

        #pragma unroll 4
        for (int step = 0; step < 32; ++step) {
            int s4 = step * 4;
            float4 ta = *(const float4*)&Tt[j][s4];
            float4 tb = *(const float4*)&Tt[j + 16][s4];
            #pragma unroll
            for (int i = 0; i < 4; ++i) {
                float4 hv = *(const float4*)&hT[g * 4 + i][s4];
                acc[i][0] = fmaf(hv.x, ta.x, fmaf(hv.y, ta.y,
                            fmaf(hv.z, ta.z, fmaf(hv.w, ta.w, acc[i][0]))));
                acc[i][1] = fmaf(hv.x, tb.x, fmaf(hv.y, tb.y,
                            fmaf(hv.z, tb.z, fmaf(hv.w, tb.w, acc[i][1]))));
            }
        }
        __syncthreads();
    }

    float* dst = xfp + ((size_t)(sc * NB + b)) * 2048;
    #pragma unroll
    for (int i = 0; i < 4; ++i) {
        dst[(g * 4 + i) * 32 + j]      = acc[i][0];
        dst[(g * 4 + i) * 32 + j + 16] = acc[i][1];
    }
}

// reduce K-split partials
__global__ __launch_bounds__(256) void k_red(const float* __restrict__ xfp,
                                             float* __restrict__ xf) {
    int idx = blockIdx.x * 256 + threadIdx.x;   // exactly 65536
    int b = idx >> 11;
    int r = idx & 2047;
    float s = 0.f;
    #pragma unroll
    for (int sc = 0; sc < NSC; ++sc)
        s += xfp[((size_t)(sc * NB + b)) * 2048 + r];
    xf[idx] = s;
}

// mode mix: of[b][o][2k] = alpha*Re, of[b][o][2k+1] = -alpha*Im
__global__ __launch_bounds__(256) void k_mix(const float* __restrict__ xf,
                                             const float* __restrict__ wr,
                                             const float* __restrict__ wi,
                                             float* __restrict__ of) {
    int tid = blockIdx.x * 256 + threadIdx.x;   // exactly 32768
    int k = tid & 15;
    int o = (tid >> 4) & 63;
    int b = tid >> 10;
    float orr = 0.f, oii = 0.f;
    const float2* xfb = (const float2*)(xf + (size_t)b * WC * NKC);
    #pragma unroll 4
    for (int i = 0; i < WC; ++i) {
        float2 cs = xfb[i * NM + k];
        float wrv = wr[(i * WC + o) * NM + k];
        float wiv = wi[(i * WC + o) * NM + k];
        orr = fmaf(cs.x, wrv, fmaf(cs.y, wiv, orr));    // xfr*wr - xfi*wi
        oii = fmaf(cs.x, wiv, fmaf(-cs.y, wrv, oii));   // xfr*wi + xfi*wr
    }
    float alpha = (k == 0 ? 1.f : 2.f) / (float)SB;
    float2 res = make_float2(alpha * orr, -alpha * oii);
    ((float2*)of)[(size_t)(b * WC + o) * NM + k] = res;
}

// fused inverse-DFT + pointwise conv + bias + relu, in-place on h
// (round-9 best-known form: full-o LDS weight block + 2-col register blocking).
__global__ __launch_bounds__(256) void k_update(float* __restrict__ h,
                                                const float* __restrict__ T,
                                                const float* __restrict__ of,
                                                const float* __restrict__ pw,
                                                const float* __restrict__ pwb,
                                                int relu) {
    __shared__ float At[96][64];   // 24 KB; At[k][o]
    int b = blockIdx.y;
    int s0 = blockIdx.x * 512 + threadIdx.x;   // second column: s0 + 256

    const float* ofb = of + (size_t)b * WC * NKC;
    for (int e = threadIdx.x; e < 96 * 64; e += 256) {
        int k = e >> 6, o = e & 63;
        At[k][o] = (k < 64) ? pw[o * 64 + k] : ofb[o * 32 + (k - 64)];
    }

    float* hcol0 = h + (size_t)b * WC * SB + s0;
    float* hcol1 = hcol0 + 256;
    float acc0[64], acc1[64];
    #pragma unroll
    for (int o = 0; o < 64; ++o) { acc0[o] = pwb[o]; acc1[o] = pwb[o]; }
    __syncthreads();

    // pointwise part: K = 64, chunks of 8
    for (int kc = 0; kc < 8; ++kc) {
        float xs0[8], xs1[8];
        #pragma unroll
        for (int u = 0; u < 8; ++u) {
            xs0[u] = hcol0[(size_t)(kc * 8 + u) * SB];
            xs1[u] = hcol1[(size_t)(kc * 8 + u) * SB];
        }
        #pragma unroll
        for (int u = 0; u < 8; ++u) {
            const float4* arow = (const float4*)At[kc * 8 + u];
            #pragma unroll
            for (int o4 = 0; o4 < 16; ++o4) {
                float4 a = arow[o4];
                acc0[o4*4+0] = fmaf(a.x, xs0[u], acc0[o4*4+0]);
                acc0[o4*4+1] = fmaf(a.y, xs0[u], acc0[o4*4+1]);
                acc0[o4*4+2] = fmaf(a.z, xs0[u], acc0[o4*4+2]);
                acc0[o4*4+3] = fmaf(a.w, xs0[u], acc0[o4*4+3]);
                acc1[o4*4+0] = fmaf(a.x, xs1[u], acc1[o4*4+0]);
                acc1[o4*4+1] = fmaf(a.y, xs1[u], acc1[o4*4+1]);
                acc1[o4*4+2] = fmaf(a.z, xs1[u], acc1[o4*4+2]);
                acc1[o4*4+3] = fmaf(a.w, xs1[u], acc1[o4*4+3]);
            }
        }
    }
    // inverse-DFT part: K = 32, chunks of 8
    const float4* Trow0 = (const float4*)(T + (size_t)s0 * NKC);
    const float4* Trow1 = (const float4*)(T + (size_t)(s0 + 256) * NKC);
    for (int kc = 0; kc < 4; ++kc) {
        float4 v0 = Trow0[kc * 2], v1 = Trow0[kc * 2 + 1];
        float4 w0 = Trow1[kc * 2], w1v = Trow1[kc * 2 + 1];
        float xs0[8] = {v0.x, v0.y, v0.z, v0.w, v1.x, v1.y, v1.z, v1.w};
        float xs1[8] = {w0.x, w0.y, w0.z, w0.w, w1v.x, w1v.y, w1v.z, w1v.w};
        #pragma unroll
        for (int u = 0; u < 8; ++u) {
            const float4* arow = (const float4*)At[64 + kc * 8 + u];
            #pragma unroll
            for (int o4 = 0; o4 < 16; ++o4) {
                float4 a = arow[o4];
                acc0[o4*4+0] = fmaf(a.x, xs0[u], acc0[o4*4+0]);
                acc0[o4*4+1] = fmaf(a.y, xs0[u], acc0[o4*4+1]);
                acc0[o4*4+2] = fmaf(a.z, xs0[u], acc0[o4*4+2]);
                acc0[o4*4+3] = fmaf(a.w, xs0[u], acc0[o4*4+3]);
                acc1[o4*4+0] = fmaf(a.x, xs1[u], acc1[o4*4+0]);
                acc1[o4*4+1] = fmaf(a.y, xs1[u], acc1[o4*4+1]);
                acc1[o4*4+2] = fmaf(a.z, xs1[u], acc1[o4*4+2]);
                acc1[o4*4+3] = fmaf(a.w, xs1[u], acc1[o4*4+3]);
            }
        }
    }

    #pragma unroll
    for (int o = 0; o < 64; ++o) {
        float v0 = acc0[o], v1 = acc1[o];
        if (relu) { v0 = fmaxf(v0, 0.f); v1 = fmaxf(v1, 0.f); }
        hcol0[(size_t)o * SB] = v0;
        hcol1[(size_t)o * SB] = v1;
    }
}

// final: NO LDS — weights via uniform s_load; hv[64]+acc[24] in regs.
// Anti-remat: empty inline-asm "+v" makes each hv value opaque so the compiler
// CANNOT re-load it per c-chunk (round-9/10: VGPR 48, 4.3GB L2 re-fetch, 120us).
__global__ __launch_bounds__(256) void k_final(const float* __restrict__ h,
                                               const float* __restrict__ fc1_w,
                                               const float* __restrict__ fc1_b,
                                               const float* __restrict__ icaT,
                                               const float* __restrict__ ica_b,
                                               float* __restrict__ out,
                                               float* __restrict__ tc) {
    int b = blockIdx.y;
    int s = blockIdx.x * 256 + threadIdx.x;

    float hv[64];
    const float* hcol = h + (size_t)b * WC * SB + s;
    #pragma unroll
    for (int i = 0; i < 64; ++i) hv[i] = hcol[(size_t)i * SB];
    #pragma unroll
    for (int i = 0; i < 64; ++i) asm volatile("" : "+v"(hv[i]));   // pin in VGPRs

    float acc[NP];
    #pragma unroll
    for (int p = 0; p < NP; ++p) acc[p] = ica_b[p];

    for (int cc = 0; cc < 16; ++cc) {
        float tv8[8];
        #pragma unroll
        for (int u = 0; u < 8; ++u) {
            int c = cc * 8 + u;
            float t = fc1_b[c];
            const float* w = fc1_w + c * WC;
            #pragma unroll
            for (int i = 0; i < 64; ++i) t = fmaf(w[i], hv[i], t);
            tv8[u] = fmaxf(t, 0.f);
        }
        #pragma unroll
        for (int u = 0; u < 8; ++u) {
            const float* e = icaT + (cc * 8 + u) * NP;
            #pragma unroll
            for (int p = 0; p < NP; ++p)
                acc[p] = fmaf(tv8[u], e[p], acc[p]);
        }
    }

    float osum = 0.f;
    #pragma unroll
    for (int p = 0; p < NP; ++p) osum += acc[p];
    size_t idx = (size_t)b * SB + s;
    out[idx] = osum;

    float4* t4 = (float4*)(tc + idx * NP);   // 96B stride; wave covers 6KB densely
    t4[0] = make_float4(acc[0],  acc[1],  acc[2],  acc[3]);
    t4[1] = make_float4(acc[4],  acc[5],  acc[6],  acc[7]);
    t4[2] = make_float4(acc[8],  acc[9],  acc[10], acc[11]);
    t4[3] = make_float4(acc[12], acc[13], acc[14], acc[15]);
    t4[4] = make_float4(acc[16], acc[17], acc[18], acc[19]);
    t4[5] = make_float4(acc[20], acc[21], acc[22], acc[23]);
}

extern "C" void kernel_launch(void* const* d_in, const int* in_sizes, int n_in,
                              void* d_out, int out_size, void* d_ws, size_t ws_size,
                              hipStream_t stream) {
    const float* x     = (const float*)d_in[0];
    const float* fc0_w = (const float*)d_in[1];
    const float* fc0_b = (const float*)d_in[2];
    const float* cwr   = (const float*)d_in[3];
    const float* cwi   = (const float*)d_in[4];
    const float* pw_w  = (const float*)d_in[5];
    const float* pw_b  = (const float*)d_in[6];
    const float* fc1_w = (const float*)d_in[7];
    const float* fc1_b = (const float*)d_in[8];
    const float* fc2_w = (const float*)d_in[9];
    const float* ica_w = (const float*)d_in[10];
    const float* ica_b = (const float*)d_in[11];

    float* out = (float*)d_out;            // (B,S,1) = 262144
    float* tc  = out + (size_t)NB * SB;    // (B,S,1,24) = 6291456

    float* ws   = (float*)d_ws;
    float* h    = ws;
    float* T    = ws + 16777216;
    float* xf   = ws + 17039360;
    float* of   = ws + 17104896;
    float* icaT = ws + 17170432;
    float* xfp  = tc;                      // k_dft partials scratch (dead until k_final)

    k_table<<<32, 256, 0, stream>>>(T);
    k_prep<<<12, 256, 0, stream>>>(ica_w, fc2_w, icaT);
    k_lift<<<dim3(32, 32), 256, 0, stream>>>(x, fc0_w, fc0_b, h);

    for (int l = 0; l < 4; ++l) {
        k_dft<<<NB * NSC, 256, 0, stream>>>(h, T, xfp);
        k_red<<<256, 256, 0, stream>>>(xfp, xf);
        k_mix<<<128, 256, 0, stream>>>(xf, cwr + (size_t)l * WC * WC * NM,
                                       cwi + (size_t)l * WC * WC * NM, of);
        k_update<<<dim3(16, 32), 256, 0, stream>>>(h, T, of,
                                                   pw_w + (size_t)l * WC * WC,
                                                   pw_b + (size_t)l * WC,
                                                   (l < 3) ? 1 : 0);
    }

    k_final<<<dim3(32, 32), 256, 0, stream>>>(h, fc1_w, fc1_b, icaT, ica_b, out, tc);
}